// Round 4
// baseline (392.447 us; speedup 1.0000x reference)
//
#include <hip/hip_runtime.h>
#include <hip/hip_bf16.h>

// Problem constants
#define B_    2
#define T_    2048
#define C_    2048
#define H_    32
#define HKV_  8
#define DH_   64
#define NQKV  3072      // C + 2*HKV*DH
#define KOFF  2048      // k columns start
#define VOFF  2560      // v columns start

typedef __attribute__((ext_vector_type(4))) float f32x4;
typedef __attribute__((ext_vector_type(16))) float f32x16;
typedef __attribute__((ext_vector_type(8))) short bf16x8;
typedef __attribute__((ext_vector_type(4))) short s16x4;

__device__ __forceinline__ float bf2f(short s) {
  union { unsigned u; float f; } v; v.u = ((unsigned)(unsigned short)s) << 16; return v.f;
}
__device__ __forceinline__ short f2bf(float f) {
  union { float f; unsigned u; } v; v.f = f;
  unsigned u = v.u + 0x7fffu + ((v.u >> 16) & 1u);   // RNE
  return (short)(u >> 16);
}
__device__ __forceinline__ unsigned pk2(float lo, float hi) {
  union { __hip_bfloat162 b; unsigned u; } c;
  c.b = __float22bfloat162_rn(make_float2(lo, hi));   // v_cvt_pk_bf16_f32
  return c.u;
}

__device__ __forceinline__ void gload_lds16(const void* g, void* l) {
  __builtin_amdgcn_global_load_lds((const __attribute__((address_space(1))) void*)g,
                                   (__attribute__((address_space(3))) void*)l, 16, 0, 0);
}

// ---------------- fp32 -> bf16 convert ----------------
__global__ void cvt_kernel(const float* __restrict__ src, short* __restrict__ dst, int n4) {
  int i = blockIdx.x * 256 + threadIdx.x;
  if (i >= n4) return;
  const float4 v = reinterpret_cast<const float4*>(src)[i];
  s16x4 o; o[0] = f2bf(v.x); o[1] = f2bf(v.y); o[2] = f2bf(v.z); o[3] = f2bf(v.w);
  reinterpret_cast<s16x4*>(dst)[i] = o;
}

// ---------------- RoPE (in-place on qkv, bf16) ----------------
__global__ void rope_kernel(short* __restrict__ qkv, const float* __restrict__ cosT,
                            const float* __restrict__ sinT) {
  const int r = blockIdx.y;                       // 0..4095 (b*T + t)
  const int p = blockIdx.x * 256 + threadIdx.x;   // 0..1279
  const int t = r & (T_ - 1);
  const int dd = p & 31;
  int col0; float sc;
  if (p < 1024) { int hh = p >> 5; col0 = hh * 64 + dd; sc = 0.18033688011112042f; }
  else          { int hh = (p - 1024) >> 5; col0 = KOFF + hh * 64 + dd; sc = 1.0f; }
  const float c = cosT[t * 32 + dd], s = sinT[t * 32 + dd];
  short* base = qkv + (size_t)r * NQKV;
  const float x1 = bf2f(base[col0]);
  const float x2 = bf2f(base[col0 + 32]);
  base[col0]      = f2bf((x1 * c - x2 * s) * sc);
  base[col0 + 32] = f2bf((x2 * c + x1 * s) * sc);
}

// ---------------- V transpose: vT[b][hk][d][t] <- V[t][d] ----------------
__global__ void vtrans_kernel(const short* __restrict__ qkv, short* __restrict__ vT) {
  __shared__ short tile[64][72];                  // +8 pad
  const int tid = threadIdx.x;
  const int tt = blockIdx.x, bh = blockIdx.y;     // tt: 64-token tile; bh = b*8+hk
  const int b = bh >> 3, hk = bh & 7;
#pragma unroll
  for (int i = 0; i < 2; ++i) {
    int c = tid + i * 256;
    int r = c >> 3, s = c & 7;
    bf16x8 v = *reinterpret_cast<const bf16x8*>(
        qkv + ((size_t)(b * T_ + tt * 64 + r)) * NQKV + VOFF + hk * 64 + s * 8);
#pragma unroll
    for (int e = 0; e < 8; ++e) tile[s * 8 + e][r] = v[e];
  }
  __syncthreads();
#pragma unroll
  for (int i = 0; i < 2; ++i) {
    int c = tid + i * 256;
    int d = c >> 3, s = c & 7;
    bf16x8 o;
#pragma unroll
    for (int e = 0; e < 8; ++e) o[e] = tile[d][s * 8 + e];
    *reinterpret_cast<bf16x8*>(vT + ((size_t)bh * 64 + d) * T_ + tt * 64 + s * 8) = o;
  }
}

// ---------------- GEMM: C[m][n] = sum_k A[m][k] * Bm[n][k] ----------------
template <int OUT_BF16>
__global__ __launch_bounds__(256) void gemm_bt(const short* __restrict__ A,
                                               const short* __restrict__ Bm,
                                               void* __restrict__ Cm,
                                               int M, int N, int K) {
  __shared__ __attribute__((aligned(16))) short Alds[128 * 32];
  __shared__ __attribute__((aligned(16))) short Blds[128 * 32];
  const int tid = threadIdx.x;
  const int w = tid >> 6, lane = tid & 63, g = lane >> 4, l15 = lane & 15;
  const int wm = (w >> 1) * 64, wn = (w & 1) * 64;

  // XCD-aware swizzle (T1): contiguous chunk of blocks per XCD
  int bid = blockIdx.y * gridDim.x + blockIdx.x;
  const int nwg = gridDim.x * gridDim.y;
  int wg = (nwg & 7) ? bid : ((bid & 7) * (nwg >> 3) + (bid >> 3));
  const int m0 = (wg / gridDim.x) * 128, n0 = (wg % gridDim.x) * 128;

  f32x4 acc[4][4] = {};

  for (int k0 = 0; k0 < K; k0 += 32) {
#pragma unroll
    for (int i = 0; i < 2; ++i) {
      int c = w * 128 + i * 64 + lane;            // chunk 0..511 (16B each)
      int row = c >> 2, slot = c & 3;
      int ks = slot ^ ((row >> 1) & 3);           // pre-swizzled source
      gload_lds16(A + (size_t)(m0 + row) * K + k0 + ks * 8,
                  Alds + (w * 128 + i * 64) * 8);
      gload_lds16(Bm + (size_t)(n0 + row) * K + k0 + ks * 8,
                  Blds + (w * 128 + i * 64) * 8);
    }
    __syncthreads();
    bf16x8 af[4], bf[4];
#pragma unroll
    for (int mi = 0; mi < 4; ++mi) {
      int ra = wm + mi * 16 + l15;
      af[mi] = *reinterpret_cast<const bf16x8*>(Alds + ra * 32 + (g ^ ((ra >> 1) & 3)) * 8);
      int rb = wn + mi * 16 + l15;
      bf[mi] = *reinterpret_cast<const bf16x8*>(Blds + rb * 32 + (g ^ ((rb >> 1) & 3)) * 8);
    }
#pragma unroll
    for (int mi = 0; mi < 4; ++mi)
#pragma unroll
      for (int ni = 0; ni < 4; ++ni)
        acc[mi][ni] = __builtin_amdgcn_mfma_f32_16x16x32_bf16(af[mi], bf[ni], acc[mi][ni], 0, 0, 0);
    __syncthreads();
  }

#pragma unroll
  for (int mi = 0; mi < 4; ++mi)
#pragma unroll
    for (int ni = 0; ni < 4; ++ni) {
      const int m = m0 + wm + mi * 16 + g * 4;    // D: row=(lane>>4)*4+reg
      const int n = n0 + wn + ni * 16 + l15;      //    col=lane&15
      if (OUT_BF16) {
        short* Cp = (short*)Cm;
#pragma unroll
        for (int r = 0; r < 4; ++r) Cp[(size_t)(m + r) * N + n] = f2bf(acc[mi][ni][r]);
      } else {
        float* Cp = (float*)Cm;
#pragma unroll
        for (int r = 0; r < 4; ++r) Cp[(size_t)(m + r) * N + n] = acc[mi][ni][r];
      }
    }
}

// ---------------- Flash attention (causal GQA), 32x32 MFMA, wave-specialized ----------------
// Block p (0..15) handles Q-tiles A=p (waves 2,3) and B=31-p (waves 0,1); each wave
// owns 32 q-rows. kv loop: nt=32-p steps; A-waves compute while t<=p (then stage-only).
// Swapped QK^T: S^T = mfma_32x32x16(K, Q^T): lane q=lane&31, j=(r&3)+8(r>>2)+4(lane>>5).
// P redistribution to PV B-frag fully in-register: cvt_pk pairs + v_permlane32_swap_b32.
// permlane32_swap semantics: swap(x,y) -> x'={x.lo,y.lo}, y'={x.hi,y.hi} (vdst.hi <-> vsrc.lo).
__global__ __launch_bounds__(256) void attn_kernel(const short* __restrict__ qkv,
                                                   const short* __restrict__ vT,
                                                   short* __restrict__ out) {
  __shared__ __attribute__((aligned(16))) short Klds[2][64 * 64];
  __shared__ __attribute__((aligned(16))) short Vlds[2][64 * 64];

  const int tid = threadIdx.x, w = tid >> 6, lane = tid & 63;
  const int l31 = lane & 31, hl = lane >> 5;

  // XCD swizzle: all 64 blocks sharing (b,hk) -> same XCD (KV slab ~1MB, L2-resident)
  const int bid = blockIdx.y * gridDim.x + blockIdx.x;   // grid (16,64) -> 1024
  const int wg = (bid & 7) * 128 + (bid >> 3);
  const int p = wg & 15, qh = wg >> 4;
  const int b = qh >> 5, h = qh & 31, hk = h >> 2;

  const int wtile = w >> 1, wq = w & 1;            // wtile 0 -> B-tile, 1 -> A-tile
  const int qt = wtile ? p : (31 - p);
  const int nt = 32 - p;
  const int myend = wtile ? (p + 1) : nt;          // #KV tiles this wave computes
  const size_t browbase = (size_t)b * T_;
  const size_t qrow = browbase + qt * 64 + wq * 32 + l31;

  // Q B-fragments: qf[s] covers k-dim d = 16s + 8*hl + e
  bf16x8 qf[4];
#pragma unroll
  for (int s = 0; s < 4; ++s)
    qf[s] = *reinterpret_cast<const bf16x8*>(qkv + qrow * NQKV + h * 64 + s * 16 + hl * 8);

  const short* kg = qkv + browbase * NQKV + KOFF + hk * 64;
  const short* vg = vT + ((size_t)(b * HKV_ + hk)) * 64 * T_;

  float m_run = -1e30f, l_run = 0.f;
  f32x16 o0 = {}, o1 = {};

  auto STAGE = [&](int kt, int buf) {
    const int kv0 = kt * 64;
#pragma unroll
    for (int i = 0; i < 2; ++i) {
      const int c = w * 128 + i * 64 + lane;       // 0..511 16B chunks
      const int j = c >> 3, slot = c & 7;
      gload_lds16(kg + (size_t)(kv0 + j) * NQKV + (slot ^ (j & 7)) * 8,
                  &Klds[buf][(w * 128 + i * 64) * 8]);
      gload_lds16(vg + (size_t)j * T_ + kv0 + (slot ^ (j & 7)) * 8,
                  &Vlds[buf][(w * 128 + i * 64) * 8]);
    }
  };

#define KFRAG(TAU, S) (*reinterpret_cast<const bf16x8*>( \
    Kc + ((TAU) * 32 + l31) * 64 + (((hl + 2 * (S)) ^ (l31 & 7)) * 8)))
#define VFRAG(DT, S) (*reinterpret_cast<const bf16x8*>( \
    Vc + ((DT) * 32 + l31) * 64 + (((hl + 2 * (S)) ^ (l31 & 7)) * 8)))

  STAGE(0, 0);
  __syncthreads();

  for (int t = 0; t < nt; ++t) {
    const int cur = t & 1;
    if (t + 1 < nt) STAGE(t + 1, cur ^ 1);
    const short* Kc = &Klds[cur][0];
    const short* Vc = &Vlds[cur][0];

    if (t < myend) {
      // ---- S^T = K · Q^T (2 j-tiles × 4 k-steps) ----
      f32x16 st0 = {}, st1 = {};
#pragma unroll
      for (int s = 0; s < 4; ++s) {
        st0 = __builtin_amdgcn_mfma_f32_32x32x16_bf16(KFRAG(0, s), qf[s], st0, 0, 0, 0);
        st1 = __builtin_amdgcn_mfma_f32_32x32x16_bf16(KFRAG(1, s), qf[s], st1, 0, 0, 0);
      }

      // ---- causal mask on the diagonal tile ----
      if (t == myend - 1) {
        const int qq = wq * 32 + l31;
#pragma unroll
        for (int r = 0; r < 16; ++r) {
          const int j0 = (r & 3) + 8 * (r >> 2) + 4 * hl;
          if (j0 > qq)      st0[r] = -1e30f;
          if (j0 + 32 > qq) st1[r] = -1e30f;
        }
      }

      // ---- online softmax, defer-max (THR=8) ----
      float tmax = -1e30f;
#pragma unroll
      for (int r = 0; r < 16; ++r) tmax = fmaxf(tmax, fmaxf(st0[r], st1[r]));
      tmax = fmaxf(tmax, __shfl_xor(tmax, 32));
      if (__any(tmax > m_run + 8.0f)) {
        const float m_new = fmaxf(m_run, tmax);
        const float corr = exp2f(m_run - m_new);
        l_run *= corr;
#pragma unroll
        for (int r = 0; r < 16; ++r) { o0[r] *= corr; o1[r] *= corr; }
        m_run = m_new;
      }
      float tsum = 0.f;
#pragma unroll
      for (int r = 0; r < 16; ++r) {
        st0[r] = exp2f(st0[r] - m_run); tsum += st0[r];
        st1[r] = exp2f(st1[r] - m_run); tsum += st1[r];
      }
      tsum += __shfl_xor(tsum, 32);
      l_run += tsum;

      // ---- pack P to bf16 pairs (j even/odd) ----
      unsigned u0[8], u1[8];
#pragma unroll
      for (int k = 0; k < 8; ++k) {
        u0[k] = pk2(st0[2 * k], st0[2 * k + 1]);
        u1[k] = pk2(st1[2 * k], st1[2 * k + 1]);
      }

      // ---- PV: O^T += V^T · P^T ; B-frag via permlane32_swap (vdst = low-j word!) ----
#define PV_STEP(S, UU)                                                        \
      {                                                                       \
        const int base_ = ((S) & 1) * 4;                                      \
        unsigned x0 = UU[base_ + 0], y0 = UU[base_ + 2];                      \
        unsigned x1 = UU[base_ + 1], y1 = UU[base_ + 3];                      \
        asm volatile("v_permlane32_swap_b32 %0, %1" : "+v"(x0), "+v"(y0));    \
        asm volatile("v_permlane32_swap_b32 %0, %1" : "+v"(x1), "+v"(y1));    \
        union { unsigned uw[4]; bf16x8 v8; } fr_;                             \
        fr_.uw[0] = x0; fr_.uw[1] = x1; fr_.uw[2] = y0; fr_.uw[3] = y1;       \
        o0 = __builtin_amdgcn_mfma_f32_32x32x16_bf16(VFRAG(0, S), fr_.v8, o0, 0, 0, 0); \
        o1 = __builtin_amdgcn_mfma_f32_32x32x16_bf16(VFRAG(1, S), fr_.v8, o1, 0, 0, 0); \
      }
      PV_STEP(0, u0)
      PV_STEP(1, u0)
      PV_STEP(2, u1)
      PV_STEP(3, u1)
#undef PV_STEP
    }
    __syncthreads();
  }

  // ---- epilogue: O^T lane q=l31; d = (r&3) + 8*(r>>2) + 4*hl + 32*dt ----
  const float inv = 1.0f / l_run;
  short* obase = out + qrow * C_ + h * 64;
  {
#pragma unroll
    for (int rr = 0; rr < 4; ++rr) {
      s16x4 ov;
#pragma unroll
      for (int e = 0; e < 4; ++e) ov[e] = f2bf(o0[rr * 4 + e] * inv);
      *reinterpret_cast<s16x4*>(obase + rr * 8 + hl * 4) = ov;
    }
#pragma unroll
    for (int rr = 0; rr < 4; ++rr) {
      s16x4 ov;
#pragma unroll
      for (int e = 0; e < 4; ++e) ov[e] = f2bf(o1[rr * 4 + e] * inv);
      *reinterpret_cast<s16x4*>(obase + 32 + rr * 8 + hl * 4) = ov;
    }
  }
#undef KFRAG
#undef VFRAG
}

// ---------------- launch ----------------
extern "C" void kernel_launch(void* const* d_in, const int* in_sizes, int n_in,
                              void* d_out, int out_size, void* d_ws, size_t ws_size,
                              hipStream_t stream) {
  const float* x    = (const float*)d_in[0];
  const float* cosT = (const float*)d_in[1];
  const float* sinT = (const float*)d_in[2];
  const float* Wq   = (const float*)d_in[3];
  const float* Wkv  = (const float*)d_in[4];
  const float* Wo   = (const float*)d_in[5];

  short* xb   = (short*)d_ws;                       // 4096x2048 (dead after gemm_qkv)
  short* wqkv = xb + (size_t)4096 * 2048;           // 3072x2048
  short* wob  = wqkv + (size_t)3072 * 2048;         // 2048x2048
  short* qkv  = wob + (size_t)2048 * 2048;          // 4096x3072
  short* aout = qkv + (size_t)4096 * 3072;          // 4096x2048
  short* vTb  = xb;                                 // 2x8x64x2048 overlays xb (safe: vtrans after gemm_qkv)

  cvt_kernel<<<8192, 256, 0, stream>>>(x, xb, 2097152);
  cvt_kernel<<<4096, 256, 0, stream>>>(Wq, wqkv, 1048576);
  cvt_kernel<<<2048, 256, 0, stream>>>(Wkv, wqkv + (size_t)2048 * 2048, 524288);
  cvt_kernel<<<4096, 256, 0, stream>>>(Wo, wob, 1048576);

  gemm_bt<1><<<dim3(24, 32), 256, 0, stream>>>(xb, wqkv, qkv, 4096, 3072, 2048);
  rope_kernel<<<dim3(5, 4096), 256, 0, stream>>>(qkv, cosT, sinT);
  vtrans_kernel<<<dim3(32, 16), 256, 0, stream>>>(qkv, vTb);
  attn_kernel<<<dim3(16, 64), 256, 0, stream>>>(qkv, vTb, aout);
  gemm_bt<0><<<dim3(16, 32), 256, 0, stream>>>(aout, wob, (float*)d_out, 4096, 2048, 2048);
}

// Round 6
// 341.196 us; speedup vs baseline: 1.1502x; 1.1502x over previous
//
#include <hip/hip_runtime.h>
#include <hip/hip_bf16.h>

// Problem constants
#define B_    2
#define T_    2048
#define C_    2048
#define H_    32
#define HKV_  8
#define DH_   64
#define NQKV  3072      // C + 2*HKV*DH
#define KOFF  2048      // k columns start
#define VOFF  2560      // v columns start

typedef __attribute__((ext_vector_type(4))) float f32x4;
typedef __attribute__((ext_vector_type(16))) float f32x16;
typedef __attribute__((ext_vector_type(8))) short bf16x8;
typedef __attribute__((ext_vector_type(4))) short s16x4;

__device__ __forceinline__ float bf2f(short s) {
  union { unsigned u; float f; } v; v.u = ((unsigned)(unsigned short)s) << 16; return v.f;
}
__device__ __forceinline__ short f2bf(float f) {
  union { float f; unsigned u; } v; v.f = f;
  unsigned u = v.u + 0x7fffu + ((v.u >> 16) & 1u);   // RNE
  return (short)(u >> 16);
}
__device__ __forceinline__ unsigned pk2(float lo, float hi) {
  union { __hip_bfloat162 b; unsigned u; } c;
  c.b = __float22bfloat162_rn(make_float2(lo, hi));   // v_cvt_pk_bf16_f32
  return c.u;
}

__device__ __forceinline__ void gload_lds16(const void* g, void* l) {
  __builtin_amdgcn_global_load_lds((const __attribute__((address_space(1))) void*)g,
                                   (__attribute__((address_space(3))) void*)l, 16, 0, 0);
}

// ---------------- fp32 -> bf16 convert, all 4 inputs in one launch ----------------
// Workspace layout is contiguous in region order, so dst group == global group id.
// Region starts (float4 groups): x 0, Wq 2097152, Wkv 3145728, Wo 3670016, end 4718592.
__global__ void cvt4_kernel(const float* __restrict__ x, const float* __restrict__ Wq,
                            const float* __restrict__ Wkv, const float* __restrict__ Wo,
                            short* __restrict__ dst) {
  const int g = blockIdx.x * 256 + threadIdx.x;
  const float* src; int off;
  if (g < 2097152)      { src = x;   off = g; }
  else if (g < 3145728) { src = Wq;  off = g - 2097152; }
  else if (g < 3670016) { src = Wkv; off = g - 3145728; }
  else                  { src = Wo;  off = g - 3670016; }
  const float4 v = reinterpret_cast<const float4*>(src)[off];
  s16x4 o; o[0] = f2bf(v.x); o[1] = f2bf(v.y); o[2] = f2bf(v.z); o[3] = f2bf(v.w);
  reinterpret_cast<s16x4*>(dst)[g] = o;
}

// ---------------- RoPE (in-place on qkv, bf16) ----------------
__global__ void rope_kernel(short* __restrict__ qkv, const float* __restrict__ cosT,
                            const float* __restrict__ sinT) {
  const int r = blockIdx.y;                       // 0..4095 (b*T + t)
  const int p = blockIdx.x * 256 + threadIdx.x;   // 0..1279
  const int t = r & (T_ - 1);
  const int dd = p & 31;
  int col0; float sc;
  if (p < 1024) { int hh = p >> 5; col0 = hh * 64 + dd; sc = 0.18033688011112042f; }
  else          { int hh = (p - 1024) >> 5; col0 = KOFF + hh * 64 + dd; sc = 1.0f; }
  const float c = cosT[t * 32 + dd], s = sinT[t * 32 + dd];
  short* base = qkv + (size_t)r * NQKV;
  const float x1 = bf2f(base[col0]);
  const float x2 = bf2f(base[col0 + 32]);
  base[col0]      = f2bf((x1 * c - x2 * s) * sc);
  base[col0 + 32] = f2bf((x2 * c + x1 * s) * sc);
}

// ---------------- V transpose: vT[b][hk][d][t] <- V[t][d] ----------------
__global__ void vtrans_kernel(const short* __restrict__ qkv, short* __restrict__ vT) {
  __shared__ short tile[64][72];                  // +8 pad
  const int tid = threadIdx.x;
  const int tt = blockIdx.x, bh = blockIdx.y;     // tt: 64-token tile; bh = b*8+hk
  const int b = bh >> 3, hk = bh & 7;
#pragma unroll
  for (int i = 0; i < 2; ++i) {
    int c = tid + i * 256;
    int r = c >> 3, s = c & 7;
    bf16x8 v = *reinterpret_cast<const bf16x8*>(
        qkv + ((size_t)(b * T_ + tt * 64 + r)) * NQKV + VOFF + hk * 64 + s * 8);
#pragma unroll
    for (int e = 0; e < 8; ++e) tile[s * 8 + e][r] = v[e];
  }
  __syncthreads();
#pragma unroll
  for (int i = 0; i < 2; ++i) {
    int c = tid + i * 256;
    int d = c >> 3, s = c & 7;
    bf16x8 o;
#pragma unroll
    for (int e = 0; e < 8; ++e) o[e] = tile[d][s * 8 + e];
    *reinterpret_cast<bf16x8*>(vT + ((size_t)bh * 64 + d) * T_ + tt * 64 + s * 8) = o;
  }
}

// ---------------- GEMM: C[m][n] = sum_k A[m][k] * Bm[n][k] ----------------
template <int OUT_BF16>
__global__ __launch_bounds__(256) void gemm_bt(const short* __restrict__ A,
                                               const short* __restrict__ Bm,
                                               void* __restrict__ Cm,
                                               int M, int N, int K) {
  __shared__ __attribute__((aligned(16))) short Alds[128 * 32];
  __shared__ __attribute__((aligned(16))) short Blds[128 * 32];
  const int tid = threadIdx.x;
  const int w = tid >> 6, lane = tid & 63, g = lane >> 4, l15 = lane & 15;
  const int wm = (w >> 1) * 64, wn = (w & 1) * 64;

  // XCD-aware swizzle (T1): contiguous chunk of blocks per XCD
  int bid = blockIdx.y * gridDim.x + blockIdx.x;
  const int nwg = gridDim.x * gridDim.y;
  int wg = (nwg & 7) ? bid : ((bid & 7) * (nwg >> 3) + (bid >> 3));
  const int m0 = (wg / gridDim.x) * 128, n0 = (wg % gridDim.x) * 128;

  f32x4 acc[4][4] = {};

  for (int k0 = 0; k0 < K; k0 += 32) {
#pragma unroll
    for (int i = 0; i < 2; ++i) {
      int c = w * 128 + i * 64 + lane;            // chunk 0..511 (16B each)
      int row = c >> 2, slot = c & 3;
      int ks = slot ^ ((row >> 1) & 3);           // pre-swizzled source
      gload_lds16(A + (size_t)(m0 + row) * K + k0 + ks * 8,
                  Alds + (w * 128 + i * 64) * 8);
      gload_lds16(Bm + (size_t)(n0 + row) * K + k0 + ks * 8,
                  Blds + (w * 128 + i * 64) * 8);
    }
    __syncthreads();
    bf16x8 af[4], bf[4];
#pragma unroll
    for (int mi = 0; mi < 4; ++mi) {
      int ra = wm + mi * 16 + l15;
      af[mi] = *reinterpret_cast<const bf16x8*>(Alds + ra * 32 + (g ^ ((ra >> 1) & 3)) * 8);
      int rb = wn + mi * 16 + l15;
      bf[mi] = *reinterpret_cast<const bf16x8*>(Blds + rb * 32 + (g ^ ((rb >> 1) & 3)) * 8);
    }
#pragma unroll
    for (int mi = 0; mi < 4; ++mi)
#pragma unroll
      for (int ni = 0; ni < 4; ++ni)
        acc[mi][ni] = __builtin_amdgcn_mfma_f32_16x16x32_bf16(af[mi], bf[ni], acc[mi][ni], 0, 0, 0);
    __syncthreads();
  }

#pragma unroll
  for (int mi = 0; mi < 4; ++mi)
#pragma unroll
    for (int ni = 0; ni < 4; ++ni) {
      const int m = m0 + wm + mi * 16 + g * 4;    // D: row=(lane>>4)*4+reg
      const int n = n0 + wn + ni * 16 + l15;      //    col=lane&15
      if (OUT_BF16) {
        short* Cp = (short*)Cm;
#pragma unroll
        for (int r = 0; r < 4; ++r) Cp[(size_t)(m + r) * N + n] = f2bf(acc[mi][ni][r]);
      } else {
        float* Cp = (float*)Cm;
#pragma unroll
        for (int r = 0; r < 4; ++r) Cp[(size_t)(m + r) * N + n] = acc[mi][ni][r];
      }
    }
}

// ---------------- Flash attention (causal GQA), 32x32 MFMA, symmetric waves ----------------
// Block = one 128-row Q-tile (qt), 4 waves x 32 q-rows each; ALL waves compute every
// kv-step (waves 0,1 skip only the final diagonal step). nt = 2*qt+2 steps of KVBLK=64.
// Swapped QK^T: S^T = mfma_32x32x16(K, Q^T): lane q=lane&31, j=(r&3)+8(r>>2)+4(lane>>5).
// P redistribution to PV B-frag in-register: cvt_pk pairs + v_permlane32_swap_b32
// (swap(x,y): x'={x.lo,y.lo}, y'={x.hi,y.hi}).
// Block mapping: per-XCD slot k -> head = k&7 (same head for all 4 co-resident blocks of
// a CU), qt from a sum-constant coset map (each CU's 4 blocks' qt sum to 30, long first).
__global__ __launch_bounds__(256) void attn_kernel(const short* __restrict__ qkv,
                                                   const short* __restrict__ vT,
                                                   short* __restrict__ out) {
  __shared__ __attribute__((aligned(16))) short Klds[2][64 * 64];
  __shared__ __attribute__((aligned(16))) short Vlds[2][64 * 64];

  const int tid = threadIdx.x, w = tid >> 6, lane = tid & 63;
  const int l31 = lane & 31, hl = lane >> 5;

  const int bid = blockIdx.x;                     // 0..1023
  const int xcd = bid & 7, k = bid >> 3;          // k: per-XCD slot 0..127
  const int qh = xcd * 8 + (k & 7);               // 8 heads per XCD (2 KV slabs, ~1MB)
  const int qi = k >> 3;                          // 0..15
  const int m_ = qi & 3, d_ = qi >> 2;            // coset map: {qt(m,0..3)} sums to 30
  const int qt = (d_ & 1) ? (2 * m_ + (d_ >> 1)) : (15 - (d_ >> 1) - 2 * m_);
  const int b = qh >> 5, h = qh & 31, hk = h >> 2;

  const int nt = 2 * qt + 2;
  const int myend = 2 * qt + (w >> 1) + 1;        // # kv tiles this wave computes
  const size_t browbase = (size_t)b * T_;
  const size_t qrow = browbase + qt * 128 + w * 32 + l31;

  // Q B-fragments: qf[s] covers k-dim d = 16s + 8*hl + e
  bf16x8 qf[4];
#pragma unroll
  for (int s = 0; s < 4; ++s)
    qf[s] = *reinterpret_cast<const bf16x8*>(qkv + qrow * NQKV + h * 64 + s * 16 + hl * 8);

  const short* kg = qkv + browbase * NQKV + KOFF + hk * 64;
  const short* vg = vT + ((size_t)(b * HKV_ + hk)) * 64 * T_;

  float m_run = -1e30f, l_run = 0.f;
  f32x16 o0 = {}, o1 = {};

  auto STAGE = [&](int kt, int buf) {
    const int kv0 = kt * 64;
#pragma unroll
    for (int i = 0; i < 2; ++i) {
      const int c = w * 128 + i * 64 + lane;       // 0..511 16B chunks
      const int j = c >> 3, slot = c & 7;
      gload_lds16(kg + (size_t)(kv0 + j) * NQKV + (slot ^ (j & 7)) * 8,
                  &Klds[buf][(w * 128 + i * 64) * 8]);
      gload_lds16(vg + (size_t)j * T_ + kv0 + (slot ^ (j & 7)) * 8,
                  &Vlds[buf][(w * 128 + i * 64) * 8]);
    }
  };

#define KFRAG(TAU, S) (*reinterpret_cast<const bf16x8*>( \
    Kc + ((TAU) * 32 + l31) * 64 + (((hl + 2 * (S)) ^ (l31 & 7)) * 8)))
#define VFRAG(DT, S) (*reinterpret_cast<const bf16x8*>( \
    Vc + ((DT) * 32 + l31) * 64 + (((hl + 2 * (S)) ^ (l31 & 7)) * 8)))

  STAGE(0, 0);
  __syncthreads();

  for (int t = 0; t < nt; ++t) {
    const int cur = t & 1;
    if (t + 1 < nt) STAGE(t + 1, cur ^ 1);
    const short* Kc = &Klds[cur][0];
    const short* Vc = &Vlds[cur][0];

    if (t < myend) {
      // ---- S^T = K · Q^T (2 j-tiles × 4 k-steps) ----
      f32x16 st0 = {}, st1 = {};
#pragma unroll
      for (int s = 0; s < 4; ++s) {
        st0 = __builtin_amdgcn_mfma_f32_32x32x16_bf16(KFRAG(0, s), qf[s], st0, 0, 0, 0);
        st1 = __builtin_amdgcn_mfma_f32_32x32x16_bf16(KFRAG(1, s), qf[s], st1, 0, 0, 0);
      }

      // ---- causal mask on this wave's diagonal tile ----
      if (t == myend - 1) {
        const int dq = ((w & 1) << 5) + l31;       // q - 64t on the diagonal tile
#pragma unroll
        for (int r = 0; r < 16; ++r) {
          const int j0 = (r & 3) + 8 * (r >> 2) + 4 * hl;
          if (j0 > dq)      st0[r] = -1e30f;
          if (j0 + 32 > dq) st1[r] = -1e30f;
        }
      }

      // ---- online softmax, defer-max (THR=8) ----
      float tmax = -1e30f;
#pragma unroll
      for (int r = 0; r < 16; ++r) tmax = fmaxf(tmax, fmaxf(st0[r], st1[r]));
      tmax = fmaxf(tmax, __shfl_xor(tmax, 32));
      if (__any(tmax > m_run + 8.0f)) {
        const float m_new = fmaxf(m_run, tmax);
        const float corr = exp2f(m_run - m_new);
        l_run *= corr;
#pragma unroll
        for (int r = 0; r < 16; ++r) { o0[r] *= corr; o1[r] *= corr; }
        m_run = m_new;
      }
      float tsum = 0.f;
#pragma unroll
      for (int r = 0; r < 16; ++r) {
        st0[r] = exp2f(st0[r] - m_run); tsum += st0[r];
        st1[r] = exp2f(st1[r] - m_run); tsum += st1[r];
      }
      tsum += __shfl_xor(tsum, 32);
      l_run += tsum;

      // ---- pack P to bf16 pairs (j even/odd) ----
      unsigned u0[8], u1[8];
#pragma unroll
      for (int kk = 0; kk < 8; ++kk) {
        u0[kk] = pk2(st0[2 * kk], st0[2 * kk + 1]);
        u1[kk] = pk2(st1[2 * kk], st1[2 * kk + 1]);
      }

      // ---- PV: O^T += V^T · P^T ; B-frag via permlane32_swap (vdst = low-j word) ----
#define PV_STEP(S, UU)                                                        \
      {                                                                       \
        const int base_ = ((S) & 1) * 4;                                      \
        unsigned x0 = UU[base_ + 0], y0 = UU[base_ + 2];                      \
        unsigned x1 = UU[base_ + 1], y1 = UU[base_ + 3];                      \
        asm volatile("v_permlane32_swap_b32 %0, %1" : "+v"(x0), "+v"(y0));    \
        asm volatile("v_permlane32_swap_b32 %0, %1" : "+v"(x1), "+v"(y1));    \
        union { unsigned uw[4]; bf16x8 v8; } fr_;                             \
        fr_.uw[0] = x0; fr_.uw[1] = x1; fr_.uw[2] = y0; fr_.uw[3] = y1;       \
        o0 = __builtin_amdgcn_mfma_f32_32x32x16_bf16(VFRAG(0, S), fr_.v8, o0, 0, 0, 0); \
        o1 = __builtin_amdgcn_mfma_f32_32x32x16_bf16(VFRAG(1, S), fr_.v8, o1, 0, 0, 0); \
      }
      PV_STEP(0, u0)
      PV_STEP(1, u0)
      PV_STEP(2, u1)
      PV_STEP(3, u1)
#undef PV_STEP
    }
    __syncthreads();
  }

  // ---- epilogue: O^T lane q=l31; d = (r&3) + 8*(r>>2) + 4*hl + 32*dt ----
  const float inv = 1.0f / l_run;
  short* obase = out + qrow * C_ + h * 64;
#pragma unroll
  for (int rr = 0; rr < 4; ++rr) {
    s16x4 ov;
#pragma unroll
    for (int e = 0; e < 4; ++e) ov[e] = f2bf(o0[rr * 4 + e] * inv);
    *reinterpret_cast<s16x4*>(obase + rr * 8 + hl * 4) = ov;
  }
#pragma unroll
  for (int rr = 0; rr < 4; ++rr) {
    s16x4 ov;
#pragma unroll
    for (int e = 0; e < 4; ++e) ov[e] = f2bf(o1[rr * 4 + e] * inv);
    *reinterpret_cast<s16x4*>(obase + 32 + rr * 8 + hl * 4) = ov;
  }
#undef KFRAG
#undef VFRAG
}

// ---------------- launch ----------------
extern "C" void kernel_launch(void* const* d_in, const int* in_sizes, int n_in,
                              void* d_out, int out_size, void* d_ws, size_t ws_size,
                              hipStream_t stream) {
  const float* x    = (const float*)d_in[0];
  const float* cosT = (const float*)d_in[1];
  const float* sinT = (const float*)d_in[2];
  const float* Wq   = (const float*)d_in[3];
  const float* Wkv  = (const float*)d_in[4];
  const float* Wo   = (const float*)d_in[5];

  short* xb   = (short*)d_ws;                       // 4096x2048 (dead after gemm_qkv)
  short* wqkv = xb + (size_t)4096 * 2048;           // 3072x2048
  short* wob  = wqkv + (size_t)3072 * 2048;         // 2048x2048
  short* qkv  = wob + (size_t)2048 * 2048;          // 4096x3072
  short* aout = qkv + (size_t)4096 * 3072;          // 4096x2048
  short* vTb  = xb;                                 // 2x8x64x2048 overlays xb (safe: vtrans after gemm_qkv)

  cvt4_kernel<<<18432, 256, 0, stream>>>(x, Wq, Wkv, Wo, (short*)d_ws);

  gemm_bt<1><<<dim3(24, 32), 256, 0, stream>>>(xb, wqkv, qkv, 4096, 3072, 2048);
  rope_kernel<<<dim3(5, 4096), 256, 0, stream>>>(qkv, cosT, sinT);
  vtrans_kernel<<<dim3(32, 16), 256, 0, stream>>>(qkv, vTb);
  attn_kernel<<<1024, 256, 0, stream>>>(qkv, vTb, aout);
  gemm_bt<0><<<dim3(16, 32), 256, 0, stream>>>(aout, wob, (float*)d_out, 4096, 2048, 2048);
}

// Round 7
// 331.689 us; speedup vs baseline: 1.1832x; 1.0287x over previous
//
#include <hip/hip_runtime.h>
#include <hip/hip_bf16.h>

// Problem constants
#define B_    2
#define T_    2048
#define C_    2048
#define H_    32
#define HKV_  8
#define DH_   64
#define NQKV  3072      // C + 2*HKV*DH
#define KOFF  2048      // k columns start
#define VOFF  2560      // v columns start

typedef __attribute__((ext_vector_type(4))) float f32x4;
typedef __attribute__((ext_vector_type(16))) float f32x16;
typedef __attribute__((ext_vector_type(8))) short bf16x8;
typedef __attribute__((ext_vector_type(4))) short s16x4;

__device__ __forceinline__ float bf2f(short s) {
  union { unsigned u; float f; } v; v.u = ((unsigned)(unsigned short)s) << 16; return v.f;
}
__device__ __forceinline__ short f2bf(float f) {
  union { float f; unsigned u; } v; v.f = f;
  unsigned u = v.u + 0x7fffu + ((v.u >> 16) & 1u);   // RNE
  return (short)(u >> 16);
}
__device__ __forceinline__ unsigned pk2(float lo, float hi) {
  union { __hip_bfloat162 b; unsigned u; } c;
  c.b = __float22bfloat162_rn(make_float2(lo, hi));   // v_cvt_pk_bf16_f32
  return c.u;
}

__device__ __forceinline__ void gload_lds16(const void* g, void* l) {
  __builtin_amdgcn_global_load_lds((const __attribute__((address_space(1))) void*)g,
                                   (__attribute__((address_space(3))) void*)l, 16, 0, 0);
}

// ---------------- fp32 -> bf16 convert, all 4 inputs in one launch ----------------
__global__ void cvt4_kernel(const float* __restrict__ x, const float* __restrict__ Wq,
                            const float* __restrict__ Wkv, const float* __restrict__ Wo,
                            short* __restrict__ dst) {
  const int g = blockIdx.x * 256 + threadIdx.x;
  const float* src; int off;
  if (g < 2097152)      { src = x;   off = g; }
  else if (g < 3145728) { src = Wq;  off = g - 2097152; }
  else if (g < 3670016) { src = Wkv; off = g - 3145728; }
  else                  { src = Wo;  off = g - 3670016; }
  const float4 v = reinterpret_cast<const float4*>(src)[off];
  s16x4 o; o[0] = f2bf(v.x); o[1] = f2bf(v.y); o[2] = f2bf(v.z); o[3] = f2bf(v.w);
  reinterpret_cast<s16x4*>(dst)[g] = o;
}

// ---------------- V transpose: vT[b][hk][d][t] <- V[t][d] ----------------
__global__ void vtrans_kernel(const short* __restrict__ qkv, short* __restrict__ vT) {
  __shared__ short tile[64][72];                  // +8 pad
  const int tid = threadIdx.x;
  const int tt = blockIdx.x, bh = blockIdx.y;     // tt: 64-token tile; bh = b*8+hk
  const int b = bh >> 3, hk = bh & 7;
#pragma unroll
  for (int i = 0; i < 2; ++i) {
    int c = tid + i * 256;
    int r = c >> 3, s = c & 7;
    bf16x8 v = *reinterpret_cast<const bf16x8*>(
        qkv + ((size_t)(b * T_ + tt * 64 + r)) * NQKV + VOFF + hk * 64 + s * 8);
#pragma unroll
    for (int e = 0; e < 8; ++e) tile[s * 8 + e][r] = v[e];
  }
  __syncthreads();
#pragma unroll
  for (int i = 0; i < 2; ++i) {
    int c = tid + i * 256;
    int d = c >> 3, s = c & 7;
    bf16x8 o;
#pragma unroll
    for (int e = 0; e < 8; ++e) o[e] = tile[d][s * 8 + e];
    *reinterpret_cast<bf16x8*>(vT + ((size_t)bh * 64 + d) * T_ + tt * 64 + s * 8) = o;
  }
}

// ---------------- GEMM: C[m][n] = sum_k A[m][k] * Bm[n][k] ----------------
// MODE 0: f32 out. MODE 1: bf16 out. MODE 2: bf16 out + fused RoPE on q/k column
// regions (q: n<2048 rotate+scale 0.125*log2e; k: 2048<=n<2560 rotate; v: pass).
// RoPE partner (d, d+32) is acc[mi][ni^2] in the SAME thread (pairs (0,2),(1,3)).
template <int MODE>
__global__ __launch_bounds__(256) void gemm_bt(const short* __restrict__ A,
                                               const short* __restrict__ Bm,
                                               void* __restrict__ Cm,
                                               const float* __restrict__ cosT,
                                               const float* __restrict__ sinT,
                                               int M, int N, int K) {
  __shared__ __attribute__((aligned(16))) short Alds[128 * 32];
  __shared__ __attribute__((aligned(16))) short Blds[128 * 32];
  const int tid = threadIdx.x;
  const int w = tid >> 6, lane = tid & 63, g = lane >> 4, l15 = lane & 15;
  const int wm = (w >> 1) * 64, wn = (w & 1) * 64;

  // XCD-aware swizzle (T1)
  int bid = blockIdx.y * gridDim.x + blockIdx.x;
  const int nwg = gridDim.x * gridDim.y;
  int wg = (nwg & 7) ? bid : ((bid & 7) * (nwg >> 3) + (bid >> 3));
  const int m0 = (wg / gridDim.x) * 128, n0 = (wg % gridDim.x) * 128;

  f32x4 acc[4][4] = {};

  for (int k0 = 0; k0 < K; k0 += 32) {
#pragma unroll
    for (int i = 0; i < 2; ++i) {
      int c = w * 128 + i * 64 + lane;            // chunk 0..511 (16B each)
      int row = c >> 2, slot = c & 3;
      int ks = slot ^ ((row >> 1) & 3);           // pre-swizzled source
      gload_lds16(A + (size_t)(m0 + row) * K + k0 + ks * 8,
                  Alds + (w * 128 + i * 64) * 8);
      gload_lds16(Bm + (size_t)(n0 + row) * K + k0 + ks * 8,
                  Blds + (w * 128 + i * 64) * 8);
    }
    __syncthreads();
    bf16x8 af[4], bf[4];
#pragma unroll
    for (int mi = 0; mi < 4; ++mi) {
      int ra = wm + mi * 16 + l15;
      af[mi] = *reinterpret_cast<const bf16x8*>(Alds + ra * 32 + (g ^ ((ra >> 1) & 3)) * 8);
      int rb = wn + mi * 16 + l15;
      bf[mi] = *reinterpret_cast<const bf16x8*>(Blds + rb * 32 + (g ^ ((rb >> 1) & 3)) * 8);
    }
#pragma unroll
    for (int mi = 0; mi < 4; ++mi)
#pragma unroll
      for (int ni = 0; ni < 4; ++ni)
        acc[mi][ni] = __builtin_amdgcn_mfma_f32_16x16x32_bf16(af[mi], bf[ni], acc[mi][ni], 0, 0, 0);
    __syncthreads();
  }

  // ---- fused RoPE (MODE 2, q/k regions only) ----
  if (MODE == 2 && n0 < VOFF) {
    const float sc = (n0 < KOFF) ? 0.18033688011112042f : 1.0f;  // 0.125*log2(e)
#pragma unroll
    for (int mi = 0; mi < 4; ++mi)
#pragma unroll
      for (int ni = 0; ni < 2; ++ni) {            // pairs (ni, ni+2)
        const int dd = ni * 16 + l15;             // d&31
#pragma unroll
        for (int r = 0; r < 4; ++r) {
          const int t = (m0 + wm + mi * 16 + g * 4 + r) & (T_ - 1);
          const float c = cosT[t * 32 + dd] * sc;
          const float s = sinT[t * 32 + dd] * sc;
          const float a = acc[mi][ni][r], b2 = acc[mi][ni + 2][r];
          acc[mi][ni][r]     = a * c - b2 * s;
          acc[mi][ni + 2][r] = b2 * c + a * s;
        }
      }
  }

#pragma unroll
  for (int mi = 0; mi < 4; ++mi)
#pragma unroll
    for (int ni = 0; ni < 4; ++ni) {
      const int m = m0 + wm + mi * 16 + g * 4;    // D: row=(lane>>4)*4+reg
      const int n = n0 + wn + ni * 16 + l15;      //    col=lane&15
      if (MODE) {
        short* Cp = (short*)Cm;
#pragma unroll
        for (int r = 0; r < 4; ++r) Cp[(size_t)(m + r) * N + n] = f2bf(acc[mi][ni][r]);
      } else {
        float* Cp = (float*)Cm;
#pragma unroll
        for (int r = 0; r < 4; ++r) Cp[(size_t)(m + r) * N + n] = acc[mi][ni][r];
      }
    }
}

// ---------------- Flash attention (causal GQA), 32x32 MFMA, equal-length blocks ----------
// 512 blocks x 4 waves. Block handles Q-tile A=p (128 rows, nTA=2p+2 kv-steps) THEN
// Q-tile B=15-p (32-2p steps) sequentially: 34 steps for EVERY block (zero tail).
// Per wave 32 q-rows; waves 0,1 own rows 0-63 (diagonal one step earlier than 2,3).
// Swapped QK^T: S^T = mfma_32x32x16(K, Q^T): lane q=lane&31, j=(r&3)+8(r>>2)+4(lane>>5).
// PV B-frag in-register: cvt_pk pairs + v_permlane32_swap_b32
// (swap(x,y): x'={x.lo,y.lo}, y'={x.hi,y.hi}).
// Mapping: xcd=bid&7, slot=bid>>3; qh=xcd*8+(slot&7) (2 KV slabs/XCD, ~1MB L2); p=slot>>3.
__global__ __launch_bounds__(256) void attn_kernel(const short* __restrict__ qkv,
                                                   const short* __restrict__ vT,
                                                   short* __restrict__ out) {
  __shared__ __attribute__((aligned(16))) short Klds[2][64 * 64];
  __shared__ __attribute__((aligned(16))) short Vlds[2][64 * 64];

  const int tid = threadIdx.x, w = tid >> 6, lane = tid & 63;
  const int l31 = lane & 31, hl = lane >> 5;

  const int bid = blockIdx.x;                     // 0..511
  const int xcd = bid & 7, slot = bid >> 3;       // slot 0..63
  const int qh = xcd * 8 + (slot & 7);
  const int p = slot >> 3;                        // 0..7
  const int qtB = 15 - p;
  const int b = qh >> 5, h = qh & 31, hk = h >> 2;

  const int nTA = 2 * p + 2;
  const int myendA = 2 * p + (w >> 1) + 1;
  const int myendB = 2 * qtB + (w >> 1) + 1;      // in B-local steps
  const size_t browbase = (size_t)b * T_;
  const size_t qrowA = browbase + p * 128 + w * 32 + l31;
  const size_t qrowB = browbase + qtB * 128 + w * 32 + l31;

  // Q B-fragments: qf[s] covers k-dim d = 16s + 8*hl + e
  bf16x8 qfA[4], qfB[4];
#pragma unroll
  for (int s = 0; s < 4; ++s) {
    qfA[s] = *reinterpret_cast<const bf16x8*>(qkv + qrowA * NQKV + h * 64 + s * 16 + hl * 8);
    qfB[s] = *reinterpret_cast<const bf16x8*>(qkv + qrowB * NQKV + h * 64 + s * 16 + hl * 8);
  }

  const short* kg = qkv + browbase * NQKV + KOFF + hk * 64;
  const short* vg = vT + ((size_t)(b * HKV_ + hk)) * 64 * T_;

  float m_run = -1e30f, l_run = 0.f;
  f32x16 o0 = {}, o1 = {};
  const short *Kc, *Vc;

  auto STAGE = [&](int kt, int buf) {
    const int kv0 = kt * 64;
#pragma unroll
    for (int i = 0; i < 2; ++i) {
      const int c = w * 128 + i * 64 + lane;       // 0..511 16B chunks
      const int j = c >> 3, sl = c & 7;
      gload_lds16(kg + (size_t)(kv0 + j) * NQKV + (sl ^ (j & 7)) * 8,
                  &Klds[buf][(w * 128 + i * 64) * 8]);
      gload_lds16(vg + (size_t)j * T_ + kv0 + (sl ^ (j & 7)) * 8,
                  &Vlds[buf][(w * 128 + i * 64) * 8]);
    }
  };

#define KFRAG(TAU, S) (*reinterpret_cast<const bf16x8*>( \
    Kc + ((TAU) * 32 + l31) * 64 + (((hl + 2 * (S)) ^ (l31 & 7)) * 8)))
#define VFRAG(DT, S) (*reinterpret_cast<const bf16x8*>( \
    Vc + ((DT) * 32 + l31) * 64 + (((hl + 2 * (S)) ^ (l31 & 7)) * 8)))

  auto TILE_STEP = [&](const bf16x8* qf, bool diag) {
    // ---- S^T = K · Q^T ----
    f32x16 st0 = {}, st1 = {};
    __builtin_amdgcn_s_setprio(1);
#pragma unroll
    for (int s = 0; s < 4; ++s) {
      st0 = __builtin_amdgcn_mfma_f32_32x32x16_bf16(KFRAG(0, s), qf[s], st0, 0, 0, 0);
      st1 = __builtin_amdgcn_mfma_f32_32x32x16_bf16(KFRAG(1, s), qf[s], st1, 0, 0, 0);
    }
    __builtin_amdgcn_s_setprio(0);

    if (diag) {
      const int dq = ((w & 1) << 5) + l31;
#pragma unroll
      for (int r = 0; r < 16; ++r) {
        const int j0 = (r & 3) + 8 * (r >> 2) + 4 * hl;
        if (j0 > dq)      st0[r] = -1e30f;
        if (j0 + 32 > dq) st1[r] = -1e30f;
      }
    }

    // ---- online softmax, defer-max (THR=8) ----
    float tmax = -1e30f;
#pragma unroll
    for (int r = 0; r < 16; ++r) tmax = fmaxf(tmax, fmaxf(st0[r], st1[r]));
    tmax = fmaxf(tmax, __shfl_xor(tmax, 32));
    if (__any(tmax > m_run + 8.0f)) {
      const float m_new = fmaxf(m_run, tmax);
      const float corr = exp2f(m_run - m_new);
      l_run *= corr;
#pragma unroll
      for (int r = 0; r < 16; ++r) { o0[r] *= corr; o1[r] *= corr; }
      m_run = m_new;
    }
    float tsum = 0.f;
#pragma unroll
    for (int r = 0; r < 16; ++r) {
      st0[r] = exp2f(st0[r] - m_run); tsum += st0[r];
      st1[r] = exp2f(st1[r] - m_run); tsum += st1[r];
    }
    tsum += __shfl_xor(tsum, 32);
    l_run += tsum;

    // ---- pack P to bf16 pairs (j even/odd) ----
    unsigned u0[8], u1[8];
#pragma unroll
    for (int kk = 0; kk < 8; ++kk) {
      u0[kk] = pk2(st0[2 * kk], st0[2 * kk + 1]);
      u1[kk] = pk2(st1[2 * kk], st1[2 * kk + 1]);
    }

    // ---- PV: O^T += V^T · P^T ----
    __builtin_amdgcn_s_setprio(1);
#define PV_STEP(S, UU)                                                        \
    {                                                                         \
      const int base_ = ((S) & 1) * 4;                                        \
      unsigned x0 = UU[base_ + 0], y0 = UU[base_ + 2];                        \
      unsigned x1 = UU[base_ + 1], y1 = UU[base_ + 3];                        \
      asm volatile("v_permlane32_swap_b32 %0, %1" : "+v"(x0), "+v"(y0));      \
      asm volatile("v_permlane32_swap_b32 %0, %1" : "+v"(x1), "+v"(y1));      \
      union { unsigned uw[4]; bf16x8 v8; } fr_;                               \
      fr_.uw[0] = x0; fr_.uw[1] = x1; fr_.uw[2] = y0; fr_.uw[3] = y1;         \
      o0 = __builtin_amdgcn_mfma_f32_32x32x16_bf16(VFRAG(0, S), fr_.v8, o0, 0, 0, 0); \
      o1 = __builtin_amdgcn_mfma_f32_32x32x16_bf16(VFRAG(1, S), fr_.v8, o1, 0, 0, 0); \
    }
    PV_STEP(0, u0)
    PV_STEP(1, u0)
    PV_STEP(2, u1)
    PV_STEP(3, u1)
#undef PV_STEP
    __builtin_amdgcn_s_setprio(0);
  };

  auto EPI = [&](size_t qrow) {
    const float inv = 1.0f / l_run;
    short* obase = out + qrow * C_ + h * 64;
#pragma unroll
    for (int rr = 0; rr < 4; ++rr) {
      s16x4 ov;
#pragma unroll
      for (int e = 0; e < 4; ++e) ov[e] = f2bf(o0[rr * 4 + e] * inv);
      *reinterpret_cast<s16x4*>(obase + rr * 8 + hl * 4) = ov;
    }
#pragma unroll
    for (int rr = 0; rr < 4; ++rr) {
      s16x4 ov;
#pragma unroll
      for (int e = 0; e < 4; ++e) ov[e] = f2bf(o1[rr * 4 + e] * inv);
      *reinterpret_cast<s16x4*>(obase + 32 + rr * 8 + hl * 4) = ov;
    }
  };

  STAGE(0, 0);
  __syncthreads();

  for (int t = 0; t < 34; ++t) {
    const int cur = t & 1;
    if (t + 1 < 34) {
      const int kn = (t + 1 < nTA) ? (t + 1) : (t + 1 - nTA);
      STAGE(kn, cur ^ 1);
    }
    Kc = &Klds[cur][0];
    Vc = &Vlds[cur][0];

    if (t < myendA) {
      TILE_STEP(qfA, t == myendA - 1);
    } else {
      if (t == myendA) {                          // flush tile A, reset state
        EPI(qrowA);
        m_run = -1e30f; l_run = 0.f;
#pragma unroll
        for (int r = 0; r < 16; ++r) { o0[r] = 0.f; o1[r] = 0.f; }
      }
      const int tb = t - nTA;
      if (tb >= 0 && tb < myendB) TILE_STEP(qfB, tb == myendB - 1);
    }
    __syncthreads();
  }

  EPI(qrowB);
#undef KFRAG
#undef VFRAG
}

// ---------------- launch ----------------
extern "C" void kernel_launch(void* const* d_in, const int* in_sizes, int n_in,
                              void* d_out, int out_size, void* d_ws, size_t ws_size,
                              hipStream_t stream) {
  const float* x    = (const float*)d_in[0];
  const float* cosT = (const float*)d_in[1];
  const float* sinT = (const float*)d_in[2];
  const float* Wq   = (const float*)d_in[3];
  const float* Wkv  = (const float*)d_in[4];
  const float* Wo   = (const float*)d_in[5];

  short* xb   = (short*)d_ws;                       // 4096x2048 (dead after gemm_qkv)
  short* wqkv = xb + (size_t)4096 * 2048;           // 3072x2048
  short* wob  = wqkv + (size_t)3072 * 2048;         // 2048x2048
  short* qkv  = wob + (size_t)2048 * 2048;          // 4096x3072
  short* aout = qkv + (size_t)4096 * 3072;          // 4096x2048
  short* vTb  = xb;                                 // vT overlays xb (safe: vtrans after gemm_qkv)

  cvt4_kernel<<<18432, 256, 0, stream>>>(x, Wq, Wkv, Wo, (short*)d_ws);

  gemm_bt<2><<<dim3(24, 32), 256, 0, stream>>>(xb, wqkv, qkv, cosT, sinT, 4096, 3072, 2048);
  vtrans_kernel<<<dim3(32, 16), 256, 0, stream>>>(qkv, vTb);
  attn_kernel<<<512, 256, 0, stream>>>(qkv, vTb, aout);
  gemm_bt<0><<<dim3(16, 32), 256, 0, stream>>>(aout, wob, (float*)d_out, cosT, sinT, 4096, 2048, 2048);
}